// Round 9
// baseline (386.187 us; speedup 1.0000x reference)
//
#include <hip/hip_runtime.h>

#define RAD 5
#define BX 64              // output tile width (pixels)
#define BY 32              // output tile height
#define PX 2               // pixels per thread in x
#define PY 2               // pixels per thread in y
#define NTX 32             // threads in x (NTX*PX == BX) -> tx spans half-wave
#define NTY 16             // threads in y (NTY*PY == BY)
#define NT 512
#define TW (BX + 2*RAD)    // 74 halo tile width
#define TH (BY + 2*RAD)    // 42 halo tile height
#define HALF (TW/2)        // 37: parity-split offset (even cols 0..36, odd 37..73)
#define NU (2*RAD + PX)    // 12 tap columns per row
#define NTROW (2*RAD + PY) // 12 tap rows serve PY=2 output rows

#define LOG2E 1.44269504f
#define CLAMP2 14426.950f  // 1e4 * log2(e)
// 128*log2(x) ~= f*(C1 + f*(C2 + f*C3)), f = x-1  (cubic ln series * 128/ln2)
#define PC1 184.664963f
#define PC2 -92.3324814f
#define PC3 61.5549876f

// kLG[|d|] = log2(exp(-d*d/8)) = -d*d/(8*ln2)
__device__ __constant__ const float kLG[6] = {
    0.0f, -0.18033688f, -0.72134752f, -1.62303192f, -2.88539008f, -4.50842200f};
// kINVD[|dy|][|dx|] = 1/sqrt(dy^2+dx^2); center sentinel 1e30 -> min() clamps
__device__ __constant__ const float kINVD[6][6] = {
    {1e30f,       1.0f,        0.5f,        0.33333333f, 0.25f,       0.2f},
    {1.0f,        0.70710678f, 0.44721360f, 0.31622777f, 0.24253563f, 0.19611614f},
    {0.5f,        0.44721360f, 0.35355339f, 0.27735010f, 0.22360680f, 0.18569534f},
    {0.33333333f, 0.31622777f, 0.27735010f, 0.23570226f, 0.2f,        0.17149859f},
    {0.25f,       0.24253563f, 0.22360680f, 0.2f,        0.17677670f, 0.15617376f},
    {0.2f,        0.19611614f, 0.18569534f, 0.17149859f, 0.15617376f, 0.14142136f}};

// One bilateral tap for output row qi (0/1), pixel p. Bit-identical math to
// r0/r5 (same op order) -> absmax unchanged.
#define TAP(qi, adx, p) do {                                                   \
    const float d1_ = fmaf(wv.x, cnx[qi][p],                                   \
                      fmaf(wv.y, cny[qi][p], fmaf(wv.z, cnz[qi][p], -1.0f)));  \
    const float f_ = fmaxf(d1_, -1.0f);                                        \
    const float dz_ = wv.w - czv[qi][p];                                       \
    const float ct_ = fmaf(-fabsf(dz_), il2##qi[adx][p], sA##qi[adx]);         \
    const float t1_ = fmaf(f_, PC3, PC2);                                      \
    const float t2_ = fmaf(f_, t1_, PC1);                                      \
    const float e_ = fmaf(f_, t2_, ct_);                                       \
    const float w_ = __builtin_amdgcn_exp2f(e_);                               \
    accx[qi][p] = fmaf(tr, w_, accx[qi][p]);                                   \
    accy[qi][p] = fmaf(tg, w_, accy[qi][p]);                                   \
    accz[qi][p] = fmaf(tb, w_, accz[qi][p]);                                   \
    accw[qi][p] += w_;                                                         \
  } while (0)

// One staged tap row feeding output rows q0/q1 (literals -> if(0) branch folds
// after parsing, so BOTH table sets must be DECLARED in the enclosing scope;
// the unused set's init is DCE'd). cv/wv read ONCE per texel.
#define ROW_BODY(Q0, Q1)                                                       \
  _Pragma("unroll")                                                            \
  for (int u = 0; u < NU; ++u) {                                               \
    const int off_ = (u >> 1) + (u & 1) * HALF;                                \
    const float4 wv = rowW[off_];                                              \
    const uint2 cv = rowC[off_];                                               \
    const float tr = __uint_as_float(cv.x << 16);                              \
    const float tg = __uint_as_float(cv.x & 0xffff0000u);                      \
    const float tb = __uint_as_float(cv.y);                                    \
    _Pragma("unroll")                                                          \
    for (int p = 0; p < PX; ++p) {                                             \
      const int dx = u - RAD - p;                                              \
      if (dx < -RAD || dx > RAD) continue;                                     \
      const int adx = dx < 0 ? -dx : dx;                                       \
      if (Q0) TAP(0, adx, p);                                                  \
      if (Q1) TAP(1, adx, p);                                                  \
    }                                                                          \
  }

#define MAKE_TABLES(qi, ADY) do {                                              \
    const float kg_ = kLG[ADY];                                                \
    const float* irow_ = kINVD[ADY];                                           \
    _Pragma("unroll")                                                          \
    for (int j = 0; j < 6; ++j) {                                              \
      sA##qi[j] = kLG[j] + kg_;                                                \
      const float iv_ = irow_[j];                                              \
      il2##qi[j][0] = fminf(rc2[qi][0] * iv_, CLAMP2);                         \
      il2##qi[j][1] = fminf(rc2[qi][1] * iv_, CLAMP2);                         \
    }                                                                          \
  } while (0)

// PY=2: each staged row feeds 2 output rows -> ds_reads/pixel 132 -> 72
// (LDS pipe ~127 -> ~64 us; r5 measured the pipe-sum regime 236 ~= 127+110).
//
// LAUNCH BOUNDS (the r6/r8 spill diagnosis): hipcc treats the 2nd arg as
// CUDA-style MIN BLOCKS PER CU. (512,4) demanded 4x512 = 32 waves/CU ->
// VGPR cap 64 (m69 steps) -> the ~90-float PY=2 live set spilled to scratch
// (r8: WRITE_SIZE 159MB vs 50MB output; VGPR pinned at exactly 64 in both
// r6 and r8). (512,2) = 2 blocks/CU, which is all LDS (74.7KB) permits
// anyway -> same real occupancy (16 waves/CU), VGPR budget 128.
__global__ __launch_bounds__(512, 2) void bilateral_kernel(
    const float* __restrict__ col, const float* __restrict__ nrm,
    const float* __restrict__ zdz, float* __restrict__ out,
    int H, int W) {
  // Parity-split layout: logical column c stored at phys (c>>1) + (c&1)*HALF.
  // Tap read logical col = 2*tx + u -> phys = tx + (u>>1) + (u&1)*HALF:
  // per half-wave a run of 32 consecutive elements -> linear, conflict-free
  // (r4-measured: 1.47e6 vs 1.76e7 for 16-lane-group geometry).
  __shared__ float4 s_w[TH][TW];  // nrm.xyz, z   (weight inputs, exact fp32)
  __shared__ uint2  s_c[TH][TW];  // col.rgb as rounded bf16: {g|r packed, b<<16}

  const int bx = blockIdx.x, by = blockIdx.y, bz = blockIdx.z;
  const int gx0 = bx * BX - RAD;
  const int gy0 = by * BY - RAD;
  const int tid = threadIdx.x;
  const int plane = bz * H * W;

  // ---- stage halo tile into LDS (OOB -> zeros => weight 0, matches mask) ----
  for (int i = tid; i < TH * TW; i += NT) {
    const int r = i / TW;
    const int c = i - r * TW;
    const int pc = (c >> 1) + (c & 1) * HALF;
    const int gy = gy0 + r, gx = gx0 + c;
    float4 wv = make_float4(0.f, 0.f, 0.f, 0.f);
    uint2 cv = make_uint2(0u, 0u);
    if ((unsigned)gy < (unsigned)H && (unsigned)gx < (unsigned)W) {
      const int pix = plane + gy * W + gx;
      const float* np_ = nrm + pix * 3;
      wv.x = np_[0]; wv.y = np_[1]; wv.z = np_[2];
      wv.w = zdz[pix * 2];  // depth
      const float* cp = col + pix * 3;
      // round-to-nearest bf16, kept in fp32 bit positions
      const unsigned ur = (__float_as_uint(cp[0]) + 0x8000u) >> 16;
      const unsigned ug = (__float_as_uint(cp[1]) + 0x8000u) & 0xffff0000u;
      const unsigned ub = (__float_as_uint(cp[2]) + 0x8000u) & 0xffff0000u;
      cv.x = ur | ug;   // r in low half (shl16 to decode), g in high half
      cv.y = ub;        // b already in fp32-high position
    }
    s_w[r][pc] = wv;
    s_c[r][pc] = cv;
  }
  __syncthreads();

  const int tx = tid & (NTX - 1);
  const int ty = tid >> 5;
  const int oy0 = by * BY + ty * PY;
  const int ox0 = bx * BX + tx * PX;

  float cnx[PY][PX], cny[PY][PX], cnz[PY][PX], czv[PY][PX], rc2[PY][PX];
  float accx[PY][PX], accy[PY][PX], accz[PY][PX], accw[PY][PX];
#pragma unroll
  for (int q = 0; q < PY; ++q) {
#pragma unroll
    for (int p = 0; p < PX; ++p) {
      const int c = tx * PX + RAD + p;
      const int pc = (c >> 1) + (c & 1) * HALF;
      const float4 wv = s_w[ty * PY + RAD + q][pc];
      cnx[q][p] = wv.x; cny[q][p] = wv.y; cnz[q][p] = wv.z;
      czv[q][p] = wv.w;
      const float cdz = zdz[(plane + (oy0 + q) * W + ox0 + p) * 2 + 1];
      rc2[q][p] = LOG2E / cdz;  // inf ok: min() clamp below
      accx[q][p] = 0.f; accy[q][p] = 0.f; accz[q][p] = 0.f; accw[q][p] = 0.f;
    }
  }

  // ---- peel trow = 0: serves q=0 only (dy = -5) ----
  {
    const float4* rowW = &s_w[ty * PY + 0][tx];
    const uint2* rowC = &s_c[ty * PY + 0][tx];
    float sA0[6], sA1[6], il20[6][PX], il21[6][PX];
    MAKE_TABLES(0, 5);
    MAKE_TABLES(1, 5);  // DCE'd: only read under if(0)
    ROW_BODY(1, 0)
  }

  // ---- interior trow = 1..10: serves both q (ady0=|trow-5|, ady1=|trow-6|,
  //      both naturally in [0,5] -> tables UNCONDITIONALLY initialized) ----
#pragma unroll 1
  for (int trow = 1; trow <= 2 * RAD; ++trow) {
    const float4* rowW = &s_w[ty * PY + trow][tx];
    const uint2* rowC = &s_c[ty * PY + trow][tx];
    const int dy0 = trow - RAD;
    const int ady0 = dy0 < 0 ? -dy0 : dy0;
    const int dy1 = trow - RAD - 1;
    const int ady1 = dy1 < 0 ? -dy1 : dy1;
    float sA0[6], sA1[6], il20[6][PX], il21[6][PX];
    MAKE_TABLES(0, ady0);
    MAKE_TABLES(1, ady1);
    ROW_BODY(1, 1)
  }

  // ---- peel trow = 11: serves q=1 only (dy = +5) ----
  {
    const float4* rowW = &s_w[ty * PY + NTROW - 1][tx];
    const uint2* rowC = &s_c[ty * PY + NTROW - 1][tx];
    float sA0[6], sA1[6], il20[6][PX], il21[6][PX];
    MAKE_TABLES(1, 5);
    MAKE_TABLES(0, 5);  // DCE'd: only read under if(0)
    ROW_BODY(0, 1)
  }

#pragma unroll
  for (int q = 0; q < PY; ++q) {
#pragma unroll
    for (int p = 0; p < PX; ++p) {
      const int pix = plane + (oy0 + q) * W + ox0 + p;
      const float inv = 1.0f / accw[q][p];  // center tap weight==1 => accw>=1
      float* op = out + pix * 3;
      op[0] = accx[q][p] * inv;
      op[1] = accy[q][p] * inv;
      op[2] = accz[q][p] * inv;
    }
  }
}

extern "C" void kernel_launch(void* const* d_in, const int* in_sizes, int n_in,
                              void* d_out, int out_size, void* d_ws, size_t ws_size,
                              hipStream_t stream) {
  const float* col = (const float*)d_in[0];
  const float* nrm = (const float*)d_in[1];
  const float* zdz = (const float*)d_in[2];
  float* out = (float*)d_out;
  const int H = 1024, W = 1024;
  const int B = in_sizes[0] / (3 * H * W);
  dim3 grid(W / BX, H / BY, B);
  bilateral_kernel<<<grid, dim3(NT), 0, stream>>>(col, nrm, zdz, out, H, W);
}

// Round 10
// 342.185 us; speedup vs baseline: 1.1286x; 1.1286x over previous
//
#include <hip/hip_runtime.h>

#define RAD 5
#define BX 64              // output tile width (pixels)
#define BY 16              // output tile height
#define PX 2               // pixels per thread in x
#define PY 2               // pixels per thread in y
#define NTX 32             // threads in x (NTX*PX == BX) -> tx spans half-wave
#define NTY 8              // threads in y (NTY*PY == BY)
#define NT 256
#define TW (BX + 2*RAD)    // 74 halo tile width
#define TH (BY + 2*RAD)    // 26 halo tile height
#define HALF (TW/2)        // 37: parity-split offset (even cols 0..36, odd 37..73)
#define NU (2*RAD + PX)    // 12 tap columns per row
#define NTROW (2*RAD + PY) // 12 tap rows serve PY=2 output rows

#define LOG2E 1.44269504f
#define CLAMP2 14426.950f  // 1e4 * log2(e)
// 128*log2(x) ~= f*(C1 + f*(C2 + f*C3)), f = x-1  (cubic ln series * 128/ln2)
#define PC1 184.664963f
#define PC2 -92.3324814f
#define PC3 61.5549876f

// kLG[|d|] = log2(exp(-d*d/8)) = -d*d/(8*ln2)
__device__ __constant__ const float kLG[6] = {
    0.0f, -0.18033688f, -0.72134752f, -1.62303192f, -2.88539008f, -4.50842200f};
// kINVD[|dy|][|dx|] = 1/sqrt(dy^2+dx^2); center sentinel 1e30 -> min() clamps
__device__ __constant__ const float kINVD[6][6] = {
    {1e30f,       1.0f,        0.5f,        0.33333333f, 0.25f,       0.2f},
    {1.0f,        0.70710678f, 0.44721360f, 0.31622777f, 0.24253563f, 0.19611614f},
    {0.5f,        0.44721360f, 0.35355339f, 0.27735010f, 0.22360680f, 0.18569534f},
    {0.33333333f, 0.31622777f, 0.27735010f, 0.23570226f, 0.2f,        0.17149859f},
    {0.25f,       0.24253563f, 0.22360680f, 0.2f,        0.17677670f, 0.15617376f},
    {0.2f,        0.19611614f, 0.18569534f, 0.17149859f, 0.15617376f, 0.14142136f}};

// One bilateral tap for output row qi (0/1), pixel p. Bit-identical math to
// r0/r5 (same op order) -> absmax unchanged.
#define TAP(qi, adx, p) do {                                                   \
    const float d1_ = fmaf(wv.x, cnx[qi][p],                                   \
                      fmaf(wv.y, cny[qi][p], fmaf(wv.z, cnz[qi][p], -1.0f)));  \
    const float f_ = fmaxf(d1_, -1.0f);                                        \
    const float dz_ = wv.w - czv[qi][p];                                       \
    const float ct_ = fmaf(-fabsf(dz_), il2##qi[adx][p], sA##qi[adx]);         \
    const float t1_ = fmaf(f_, PC3, PC2);                                      \
    const float t2_ = fmaf(f_, t1_, PC1);                                      \
    const float e_ = fmaf(f_, t2_, ct_);                                       \
    const float w_ = __builtin_amdgcn_exp2f(e_);                               \
    accx[qi][p] = fmaf(tr, w_, accx[qi][p]);                                   \
    accy[qi][p] = fmaf(tg, w_, accy[qi][p]);                                   \
    accz[qi][p] = fmaf(tb, w_, accz[qi][p]);                                   \
    accw[qi][p] += w_;                                                         \
  } while (0)

// One staged tap row feeding output rows q0/q1 (literals -> if(0) branch folds
// after parsing, so BOTH table sets must be DECLARED in the enclosing scope;
// the unused set's init is DCE'd). cv/wv read ONCE per texel.
#define ROW_BODY(Q0, Q1)                                                       \
  _Pragma("unroll")                                                            \
  for (int u = 0; u < NU; ++u) {                                               \
    const int off_ = (u >> 1) + (u & 1) * HALF;                                \
    const float4 wv = rowW[off_];                                              \
    const uint2 cv = rowC[off_];                                               \
    const float tr = __uint_as_float(cv.x << 16);                              \
    const float tg = __uint_as_float(cv.x & 0xffff0000u);                      \
    const float tb = __uint_as_float(cv.y);                                    \
    _Pragma("unroll")                                                          \
    for (int p = 0; p < PX; ++p) {                                             \
      const int dx = u - RAD - p;                                              \
      if (dx < -RAD || dx > RAD) continue;                                     \
      const int adx = dx < 0 ? -dx : dx;                                       \
      if (Q0) TAP(0, adx, p);                                                  \
      if (Q1) TAP(1, adx, p);                                                  \
    }                                                                          \
  }

#define MAKE_TABLES(qi, ADY) do {                                              \
    const float kg_ = kLG[ADY];                                                \
    const float* irow_ = kINVD[ADY];                                           \
    _Pragma("unroll")                                                          \
    for (int j = 0; j < 6; ++j) {                                              \
      sA##qi[j] = kLG[j] + kg_;                                                \
      const float iv_ = irow_[j];                                              \
      il2##qi[j][0] = fminf(rc2[qi][0] * iv_, CLAMP2);                         \
      il2##qi[j][1] = fminf(rc2[qi][1] * iv_, CLAMP2);                         \
    }                                                                          \
  } while (0)

// PY=2 at r5's residency envelope: 256 threads, halo 74x26 -> LDS 46.2 KB
// (r5's exact footprint, 3 blocks/CU) with each staged row feeding 2 output
// rows -> ds_reads/pixel 132 -> 66 (LDS pipe ~127 -> ~64 us).
// Session law (r5 vs r8/r9): duration tracks resident waves; residency dies
// with >64KB-class LDS blocks (r9: 74.7KB, occ 19.6, 307us) while 46.6KB at
// VGPR<=128 held 46.7% (r5, 236us). (256,4): 16 waves/CU floor under BOTH
// launch_bounds semantics (4 blocks x 4 waves, or 4 waves/EU) -> VGPR cap
// 128; PY=2 live set measured 92 (r9) -> fits, no spill.
__global__ __launch_bounds__(256, 4) void bilateral_kernel(
    const float* __restrict__ col, const float* __restrict__ nrm,
    const float* __restrict__ zdz, float* __restrict__ out,
    int H, int W) {
  // Parity-split layout: logical column c stored at phys (c>>1) + (c&1)*HALF.
  // Tap read logical col = 2*tx + u -> phys = tx + (u>>1) + (u&1)*HALF:
  // per half-wave a run of 32 consecutive elements -> linear, conflict-free
  // (r4-measured: 1.47e6 vs 1.76e7 for 16-lane-group geometry).
  __shared__ float4 s_w[TH][TW];  // nrm.xyz, z   (weight inputs, exact fp32)
  __shared__ uint2  s_c[TH][TW];  // col.rgb as rounded bf16: {g|r packed, b<<16}

  const int bx = blockIdx.x, by = blockIdx.y, bz = blockIdx.z;
  const int gx0 = bx * BX - RAD;
  const int gy0 = by * BY - RAD;
  const int tid = threadIdx.x;
  const int plane = bz * H * W;

  // ---- stage halo tile into LDS (OOB -> zeros => weight 0, matches mask) ----
  for (int i = tid; i < TH * TW; i += NT) {
    const int r = i / TW;
    const int c = i - r * TW;
    const int pc = (c >> 1) + (c & 1) * HALF;
    const int gy = gy0 + r, gx = gx0 + c;
    float4 wv = make_float4(0.f, 0.f, 0.f, 0.f);
    uint2 cv = make_uint2(0u, 0u);
    if ((unsigned)gy < (unsigned)H && (unsigned)gx < (unsigned)W) {
      const int pix = plane + gy * W + gx;
      const float* np_ = nrm + pix * 3;
      wv.x = np_[0]; wv.y = np_[1]; wv.z = np_[2];
      wv.w = zdz[pix * 2];  // depth
      const float* cp = col + pix * 3;
      // round-to-nearest bf16, kept in fp32 bit positions
      const unsigned ur = (__float_as_uint(cp[0]) + 0x8000u) >> 16;
      const unsigned ug = (__float_as_uint(cp[1]) + 0x8000u) & 0xffff0000u;
      const unsigned ub = (__float_as_uint(cp[2]) + 0x8000u) & 0xffff0000u;
      cv.x = ur | ug;   // r in low half (shl16 to decode), g in high half
      cv.y = ub;        // b already in fp32-high position
    }
    s_w[r][pc] = wv;
    s_c[r][pc] = cv;
  }
  __syncthreads();

  const int tx = tid & (NTX - 1);
  const int ty = tid >> 5;            // 0..7
  const int oy0 = by * BY + ty * PY;
  const int ox0 = bx * BX + tx * PX;

  float cnx[PY][PX], cny[PY][PX], cnz[PY][PX], czv[PY][PX], rc2[PY][PX];
  float accx[PY][PX], accy[PY][PX], accz[PY][PX], accw[PY][PX];
#pragma unroll
  for (int q = 0; q < PY; ++q) {
#pragma unroll
    for (int p = 0; p < PX; ++p) {
      const int c = tx * PX + RAD + p;
      const int pc = (c >> 1) + (c & 1) * HALF;
      const float4 wv = s_w[ty * PY + RAD + q][pc];
      cnx[q][p] = wv.x; cny[q][p] = wv.y; cnz[q][p] = wv.z;
      czv[q][p] = wv.w;
      const float cdz = zdz[(plane + (oy0 + q) * W + ox0 + p) * 2 + 1];
      rc2[q][p] = LOG2E / cdz;  // inf ok: min() clamp below
      accx[q][p] = 0.f; accy[q][p] = 0.f; accz[q][p] = 0.f; accw[q][p] = 0.f;
    }
  }

  // ---- peel trow = 0: serves q=0 only (dy = -5) ----
  {
    const float4* rowW = &s_w[ty * PY + 0][tx];
    const uint2* rowC = &s_c[ty * PY + 0][tx];
    float sA0[6], sA1[6], il20[6][PX], il21[6][PX];
    MAKE_TABLES(0, 5);
    MAKE_TABLES(1, 5);  // DCE'd: only read under if(0)
    ROW_BODY(1, 0)
  }

  // ---- interior trow = 1..10: serves both q (ady0=|trow-5|, ady1=|trow-6|,
  //      both naturally in [0,5] -> tables UNCONDITIONALLY initialized) ----
#pragma unroll 1
  for (int trow = 1; trow <= 2 * RAD; ++trow) {
    const float4* rowW = &s_w[ty * PY + trow][tx];
    const uint2* rowC = &s_c[ty * PY + trow][tx];
    const int dy0 = trow - RAD;
    const int ady0 = dy0 < 0 ? -dy0 : dy0;
    const int dy1 = trow - RAD - 1;
    const int ady1 = dy1 < 0 ? -dy1 : dy1;
    float sA0[6], sA1[6], il20[6][PX], il21[6][PX];
    MAKE_TABLES(0, ady0);
    MAKE_TABLES(1, ady1);
    ROW_BODY(1, 1)
  }

  // ---- peel trow = 11: serves q=1 only (dy = +5) ----
  {
    const float4* rowW = &s_w[ty * PY + NTROW - 1][tx];
    const uint2* rowC = &s_c[ty * PY + NTROW - 1][tx];
    float sA0[6], sA1[6], il20[6][PX], il21[6][PX];
    MAKE_TABLES(1, 5);
    MAKE_TABLES(0, 5);  // DCE'd: only read under if(0)
    ROW_BODY(0, 1)
  }

#pragma unroll
  for (int q = 0; q < PY; ++q) {
#pragma unroll
    for (int p = 0; p < PX; ++p) {
      const int pix = plane + (oy0 + q) * W + ox0 + p;
      const float inv = 1.0f / accw[q][p];  // center tap weight==1 => accw>=1
      float* op = out + pix * 3;
      op[0] = accx[q][p] * inv;
      op[1] = accy[q][p] * inv;
      op[2] = accz[q][p] * inv;
    }
  }
}

extern "C" void kernel_launch(void* const* d_in, const int* in_sizes, int n_in,
                              void* d_out, int out_size, void* d_ws, size_t ws_size,
                              hipStream_t stream) {
  const float* col = (const float*)d_in[0];
  const float* nrm = (const float*)d_in[1];
  const float* zdz = (const float*)d_in[2];
  float* out = (float*)d_out;
  const int H = 1024, W = 1024;
  const int B = in_sizes[0] / (3 * H * W);
  dim3 grid(W / BX, H / BY, B);
  bilateral_kernel<<<grid, dim3(NT), 0, stream>>>(col, nrm, zdz, out, H, W);
}

// Round 11
// 314.189 us; speedup vs baseline: 1.2292x; 1.0891x over previous
//
#include <hip/hip_runtime.h>

#define RAD 5
#define BX 64              // output tile width (pixels)
#define BY 16              // output tile height
#define PX 2               // pixels per thread in x
#define NTX 32             // threads in x (NTX*PX == BX) -> tx spans half-wave
#define NTY 16             // threads in y
#define NT 512
#define TW (BX + 2*RAD)    // 74 halo tile width
#define TH (BY + 2*RAD)    // 26 halo tile height
#define HALF (TW/2)        // 37: parity-split offset (even cols 0..36, odd 37..73)
#define NU (2*RAD + PX)    // 12 tap columns per row

#define LOG2E 1.44269504f
#define CLAMP2 14426.950f  // 1e4 * log2(e)
// 128*log2(x) ~= f*(C1 + f*(C2 + f*C3)), f = x-1  (cubic ln series * 128/ln2)
#define PC1 184.664963f
#define PC2 -92.3324814f
#define PC3 61.5549876f

// kLG[|d|] = log2(exp(-d*d/8)) = -d*d/(8*ln2)
__device__ __constant__ const float kLG[6] = {
    0.0f, -0.18033688f, -0.72134752f, -1.62303192f, -2.88539008f, -4.50842200f};
// kINVD[|dy|][|dx|] = 1/sqrt(dy^2+dx^2); center sentinel 1e30 -> min() clamps
__device__ __constant__ const float kINVD[6][6] = {
    {1e30f,       1.0f,        0.5f,        0.33333333f, 0.25f,       0.2f},
    {1.0f,        0.70710678f, 0.44721360f, 0.31622777f, 0.24253563f, 0.19611614f},
    {0.5f,        0.44721360f, 0.35355339f, 0.27735010f, 0.22360680f, 0.18569534f},
    {0.33333333f, 0.31622777f, 0.27735010f, 0.23570226f, 0.2f,        0.17149859f},
    {0.25f,       0.24253563f, 0.22360680f, 0.2f,        0.17677670f, 0.15617376f},
    {0.2f,        0.19611614f, 0.18569534f, 0.17149859f, 0.15617376f, 0.14142136f}};

// LAUNCH BOUNDS: hipcc's 2nd arg = MIN BLOCKS PER CU (session-measured:
// (512,4) pinned VGPR at exactly 64 = 2048/32-waves in r5/r6/r8; (512,2)
// gave 92 in r9 with no spill). (512,2) -> VGPR budget 128, which is what
// lets the 12-texel row batch below actually stay in registers: r5's
// identical batch at (512,4) was re-sunk to read->wait->use (VGPR 48,
// dur 236 = exact LDS+VALU pipe sum, zero overlap). This round is the
// single-token A/B: same source as r5, budget 128.
__global__ __launch_bounds__(512, 2) void bilateral_kernel(
    const float* __restrict__ col, const float* __restrict__ nrm,
    const float* __restrict__ zdz, float* __restrict__ out,
    int H, int W) {
  // Parity-split layout: logical column c stored at phys (c>>1) + (c&1)*HALF.
  // Tap read logical col = 2*tx + u -> phys = tx + (u>>1) + (u&1)*HALF:
  // per half-wave a run of 32 consecutive elements -> linear, conflict-free
  // (r4-measured: 1.47e6 vs 1.76e7 for 16-lane-group geometry).
  __shared__ float4 s_w[TH][TW];  // nrm.xyz, z   (weight inputs, exact fp32)
  __shared__ uint2  s_c[TH][TW];  // col.rgb as rounded bf16: {g|r packed, b<<16}

  const int bx = blockIdx.x, by = blockIdx.y, bz = blockIdx.z;
  const int gx0 = bx * BX - RAD;
  const int gy0 = by * BY - RAD;
  const int tid = threadIdx.x;
  const int plane = bz * H * W;

  // ---- stage halo tile into LDS (OOB -> zeros => weight 0, matches mask) ----
  for (int i = tid; i < TH * TW; i += NT) {
    const int r = i / TW;
    const int c = i - r * TW;
    const int pc = (c >> 1) + (c & 1) * HALF;
    const int gy = gy0 + r, gx = gx0 + c;
    float4 wv = make_float4(0.f, 0.f, 0.f, 0.f);
    uint2 cv = make_uint2(0u, 0u);
    if ((unsigned)gy < (unsigned)H && (unsigned)gx < (unsigned)W) {
      const int pix = plane + gy * W + gx;
      const float* np_ = nrm + pix * 3;
      wv.x = np_[0]; wv.y = np_[1]; wv.z = np_[2];
      wv.w = zdz[pix * 2];  // depth
      const float* cp = col + pix * 3;
      // round-to-nearest bf16, kept in fp32 bit positions
      const unsigned ur = (__float_as_uint(cp[0]) + 0x8000u) >> 16;
      const unsigned ug = (__float_as_uint(cp[1]) + 0x8000u) & 0xffff0000u;
      const unsigned ub = (__float_as_uint(cp[2]) + 0x8000u) & 0xffff0000u;
      cv.x = ur | ug;   // r in low half (shl16 to decode), g in high half
      cv.y = ub;        // b already in fp32-high position
    }
    s_w[r][pc] = wv;
    s_c[r][pc] = cv;
  }
  __syncthreads();

  const int tx = tid & (NTX - 1);
  const int ty = tid >> 5;
  const int ly = ty + RAD;
  const int oy = by * BY + ty;
  const int ox0 = bx * BX + tx * PX;

  float cnx[PX], cny[PX], cnz[PX], czv[PX], rc2[PX];
  float accx[PX], accy[PX], accz[PX], accw[PX];
#pragma unroll
  for (int p = 0; p < PX; ++p) {
    const int c = tx * PX + RAD + p;
    const int pc = (c >> 1) + (c & 1) * HALF;
    const float4 wv = s_w[ly][pc];
    cnx[p] = wv.x; cny[p] = wv.y; cnz[p] = wv.z;
    czv[p] = wv.w;
    const float cdz = zdz[(plane + oy * W + ox0 + p) * 2 + 1];  // center |dz|
    rc2[p] = LOG2E / cdz;  // inf ok: min() clamp below
    accx[p] = 0.f; accy[p] = 0.f; accz[p] = 0.f; accw[p] = 0.f;
  }

#pragma unroll 1
  for (int dy = -RAD; dy <= RAD; ++dy) {
    const int ady = dy < 0 ? -dy : dy;

    // ---- batch-prefetch the whole tap row into registers FIRST ----
    // 12 x (b128 + b64) issued back-to-back (72 VGPRs of tap data in
    // flight); the il2s table math below overlaps the LDS latency, and the
    // compute loop gets counted-lgkmcnt waits instead of one
    // read->wait(0)->use stall per texel. Requires the 128-VGPR budget:
    // at budget 64 the compiler provably re-sinks this (r5).
    const float4* rowW = &s_w[ly + dy][tx];
    const uint2* rowC = &s_c[ly + dy][tx];
    float4 wvs[NU];
    uint2 cvs[NU];
#pragma unroll
    for (int u = 0; u < NU; ++u) {
      const int off = (u >> 1) + (u & 1) * HALF;  // compile-time per u
      wvs[u] = rowW[off];
      cvs[u] = rowC[off];
    }

    const float kg_ady = kLG[ady];      // wave-uniform (SGPR)
    const float* irow = kINVD[ady];     // wave-uniform row pointer
    float sA[6];                         // kLG[adx]+kLG[ady]  (SGPR)
    float il2s[6][PX];
#pragma unroll
    for (int j = 0; j < 6; ++j) {
      sA[j] = kLG[j] + kg_ady;
      const float iv = irow[j];
#pragma unroll
      for (int p = 0; p < PX; ++p) il2s[j][p] = fminf(rc2[p] * iv, CLAMP2);
    }

#pragma unroll
    for (int u = 0; u < NU; ++u) {  // 12 tap columns serve PX pixels
      const float4 wv = wvs[u];
      const uint2 cv = cvs[u];
      const float tr = __uint_as_float(cv.x << 16);
      const float tg = __uint_as_float(cv.x & 0xffff0000u);
      const float tb = __uint_as_float(cv.y);
#pragma unroll
      for (int p = 0; p < PX; ++p) {
        const int dx = u - RAD - p;
        if (dx < -RAD || dx > RAD) continue;
        const int adx = dx < 0 ? -dx : dx;
        // f = clamp(dot,?) - 1, with the -1 folded into the dot chain
        const float d1 = fmaf(wv.x, cnx[p],
                         fmaf(wv.y, cny[p], fmaf(wv.z, cnz[p], -1.0f)));
        const float f = fmaxf(d1, -1.0f);
        // ct = sA - |z_t - z_c| * il2   (exponent sans normal term)
        const float dz = wv.w - czv[p];
        const float ct = fmaf(-fabsf(dz), il2s[adx][p], sA[adx]);
        // e = 128*log2(dot) + ct via cubic in f; f=-1 -> e<=-338 -> w==0
        const float t1 = fmaf(f, PC3, PC2);
        const float t2 = fmaf(f, t1, PC1);
        const float e = fmaf(f, t2, ct);
        const float w = __builtin_amdgcn_exp2f(e);
        accx[p] = fmaf(tr, w, accx[p]);
        accy[p] = fmaf(tg, w, accy[p]);
        accz[p] = fmaf(tb, w, accz[p]);
        accw[p] += w;
      }
    }
  }

#pragma unroll
  for (int p = 0; p < PX; ++p) {
    const int pix = plane + oy * W + ox0 + p;
    const float inv = 1.0f / accw[p];  // center tap weight==1 => accw>=1
    float* op = out + pix * 3;
    op[0] = accx[p] * inv;
    op[1] = accy[p] * inv;
    op[2] = accz[p] * inv;
  }
}

extern "C" void kernel_launch(void* const* d_in, const int* in_sizes, int n_in,
                              void* d_out, int out_size, void* d_ws, size_t ws_size,
                              hipStream_t stream) {
  const float* col = (const float*)d_in[0];
  const float* nrm = (const float*)d_in[1];
  const float* zdz = (const float*)d_in[2];
  float* out = (float*)d_out;
  const int H = 1024, W = 1024;
  const int B = in_sizes[0] / (3 * H * W);
  dim3 grid(W / BX, H / BY, B);
  bilateral_kernel<<<grid, dim3(NT), 0, stream>>>(col, nrm, zdz, out, H, W);
}